// Round 15
// baseline (133.474 us; speedup 1.0000x reference)
//
#include <hip/hip_runtime.h>
#include <hip/hip_fp16.h>
#include <math.h>

#define BLK 256

typedef _Float16 half8 __attribute__((ext_vector_type(8)));
typedef float f32x4 __attribute__((ext_vector_type(4)));
typedef float f32x2 __attribute__((ext_vector_type(2)));

// ---------------- init: zero deg + convert/transpose weights ----------------
__global__ void init_kernel(int4* __restrict__ deg4, int n4,
                            const float* __restrict__ W0, const float* __restrict__ W1,
                            __half* __restrict__ wt0, __half* __restrict__ wt1) {
    int t = blockIdx.x * blockDim.x + threadIdx.x;
    if (t < n4) {
        deg4[t] = make_int4(0, 0, 0, 0);
    } else {
        int u = t - n4;
        if (u < 128 * 128) {
            int c = u >> 7, k = u & 127;
            wt0[u] = __float2half(W0[k * 128 + c]);
        } else if (u < 128 * 128 + 64 * 128) {
            int v = u - 128 * 128;
            int c = v >> 7, k = v & 127;
            wt1[v] = __float2half(W1[k * 64 + c]);
        }
    }
}

// 4 edges/thread: 4 independent atomics in flight per lane.
__global__ void deg_rank_kernel(const int* __restrict__ dst, int* __restrict__ deg,
                                int* __restrict__ rank, int E) {
    int t4 = blockIdx.x * blockDim.x + threadIdx.x;
    int e0 = t4 * 4;
    if (e0 + 4 <= E) {
        int4 d = *(const int4*)&dst[e0];
        int r0 = atomicAdd(&deg[d.x], 1);
        int r1 = atomicAdd(&deg[d.y], 1);
        int r2 = atomicAdd(&deg[d.z], 1);
        int r3 = atomicAdd(&deg[d.w], 1);
        *(int4*)&rank[e0] = make_int4(r0, r1, r2, r3);
    } else {
        for (int e = e0; e < E; ++e) rank[e] = atomicAdd(&deg[dst[e]], 1);
    }
}

// Exclusive scan of deg into rowptr (1024 elems/block) + dinv = rsqrt(deg+1).
__global__ void scan1_kernel(const int* __restrict__ deg, int* __restrict__ rowptr,
                             int* __restrict__ bsum, float* __restrict__ dinv, int n) {
    __shared__ int s[BLK];
    int tid = threadIdx.x;
    int base = blockIdx.x * 1024 + tid * 4;
    int v[4];
    int sum = 0;
    #pragma unroll
    for (int j = 0; j < 4; ++j) {
        v[j] = (base + j < n) ? deg[base + j] : 0;
        sum += v[j];
    }
    #pragma unroll
    for (int j = 0; j < 4; ++j)
        if (base + j < n) dinv[base + j] = rsqrtf((float)(v[j] + 1));
    s[tid] = sum;
    __syncthreads();
    #pragma unroll
    for (int off = 1; off < BLK; off <<= 1) {
        int t = 0;
        if (tid >= off) t = s[tid - off];
        __syncthreads();
        if (tid >= off) s[tid] += t;
        __syncthreads();
    }
    int run = s[tid] - sum;
    #pragma unroll
    for (int j = 0; j < 4; ++j) {
        if (base + j < n) rowptr[base + j] = run;
        run += v[j];
    }
    if (tid == BLK - 1) bsum[blockIdx.x] = s[BLK - 1];
}

// Fused scan2+scan3: every block redundantly scans bsum (nb <= 64), finalizes rowptr.
__global__ void scan23_kernel(int* __restrict__ rowptr, const int* __restrict__ bsum,
                              int n, int E, int nb) {
    __shared__ int s[64];
    int tid = threadIdx.x;
    if (tid < 64) s[tid] = (tid < nb) ? bsum[tid] : 0;
    __syncthreads();
    #pragma unroll
    for (int off = 1; off < 64; off <<= 1) {
        int t = 0;
        if (tid < 64 && tid >= off) t = s[tid - off];
        __syncthreads();
        if (tid < 64 && tid >= off) s[tid] += t;
        __syncthreads();
    }
    int i = blockIdx.x * blockDim.x + tid;
    if (i < n) {
        int b = i >> 10;
        int add = (b == 0) ? 0 : s[b - 1];
        rowptr[i] += add;
    }
    if (i == 0) rowptr[n] = E;
}

// ---------------- fused: CSR fill (atomic-free, 4 edges/thread) + MFMA GEMM layer 1 ----------------
// Layer-1 hs stored fp8 e4m3 (proven absmax-neutral: sigmoid squashes the rounding).

__device__ inline void gemm_mfma_body_f32(const float* __restrict__ x,
                                          const __half* __restrict__ wt,
                                          const float* __restrict__ dinv,
                                          unsigned char* __restrict__ hs8, int n, int bid) {
    const int tid   = threadIdx.x;
    const int wave  = tid >> 6;
    const int lane  = tid & 63;
    const int l15   = lane & 15;
    const int khalf = lane >> 4;

    const int rowA = bid * 64 + wave * 16 + l15;

    half8 a[4];
    #pragma unroll
    for (int ks = 0; ks < 4; ++ks) {
        if (rowA < n) {
            const float* px = &x[(size_t)rowA * 128 + ks * 32 + khalf * 8];
            float4 f0 = *(const float4*)&px[0];
            float4 f1 = *(const float4*)&px[4];
            union { half8 h8; __half2 h2[4]; } u;
            u.h2[0] = __floats2half2_rn(f0.x, f0.y);
            u.h2[1] = __floats2half2_rn(f0.z, f0.w);
            u.h2[2] = __floats2half2_rn(f1.x, f1.y);
            u.h2[3] = __floats2half2_rn(f1.z, f1.w);
            a[ks] = u.h8;
        } else {
            half8 z = {0, 0, 0, 0, 0, 0, 0, 0};
            a[ks] = z;
        }
    }

    const int crow0 = bid * 64 + wave * 16 + khalf * 4;
    float dv[4];
    #pragma unroll
    for (int i = 0; i < 4; ++i) dv[i] = (crow0 + i < n) ? dinv[crow0 + i] : 0.0f;

    #pragma unroll
    for (int ct = 0; ct < 8; ++ct) {          // OUTC = 128
        f32x4 acc = {0.f, 0.f, 0.f, 0.f};
        #pragma unroll
        for (int ks = 0; ks < 4; ++ks) {
            half8 b = *(const half8*)&wt[(size_t)(ct * 16 + l15) * 128 + ks * 32 + khalf * 8];
            acc = __builtin_amdgcn_mfma_f32_16x16x32_f16(a[ks], b, acc, 0, 0, 0);
        }
        const int col = ct * 16 + l15;
        #pragma unroll
        for (int i = 0; i < 4; ++i) {
            int r = crow0 + i;
            if (r < n) {
                float f = acc[i] * dv[i];
                unsigned int b8 = (unsigned int)__builtin_amdgcn_cvt_pk_fp8_f32(f, f, 0, 0);
                hs8[(size_t)r * 128 + col] = (unsigned char)(b8 & 0xff);
            }
        }
    }
}

__global__ __launch_bounds__(256) void fill_gemm1_kernel(
    const int* __restrict__ src, const int* __restrict__ dst,
    const int* __restrict__ rank, const int* __restrict__ rowptr,
    int* __restrict__ csr_src, int E,
    const float* __restrict__ x, const __half* __restrict__ wt0,
    const float* __restrict__ dinv, unsigned char* __restrict__ hs8, int n, int ggrid) {
    if ((int)blockIdx.x < ggrid) {
        gemm_mfma_body_f32(x, wt0, dinv, hs8, n, blockIdx.x);
    } else {
        int t4 = (blockIdx.x - ggrid) * BLK + threadIdx.x;
        int e0 = t4 * 4;
        if (e0 + 4 <= E) {
            int4 d = *(const int4*)&dst[e0];
            int4 s = *(const int4*)&src[e0];
            int4 r = *(const int4*)&rank[e0];
            int p0 = rowptr[d.x] + r.x;
            int p1 = rowptr[d.y] + r.y;
            int p2 = rowptr[d.z] + r.z;
            int p3 = rowptr[d.w] + r.w;
            csr_src[p0] = s.x;
            csr_src[p1] = s.y;
            csr_src[p2] = s.z;
            csr_src[p3] = s.w;
        } else {
            for (int e = e0; e < E; ++e)
                csr_src[rowptr[dst[e]] + rank[e]] = src[e];
        }
    }
}

// ---------------- MFMA GEMM layer 2 (fp16 input, fp16 output) ----------------

template <int OUTC>
__global__ __launch_bounds__(256) void gemm_mfma_kernel(const __half* __restrict__ x,
                                                        const __half* __restrict__ wt,
                                                        const float* __restrict__ dinv,
                                                        __half* __restrict__ hs, int n) {
    const int tid   = threadIdx.x;
    const int wave  = tid >> 6;
    const int lane  = tid & 63;
    const int l15   = lane & 15;
    const int khalf = lane >> 4;

    const int rowA = blockIdx.x * 64 + wave * 16 + l15;

    half8 a[4];
    #pragma unroll
    for (int ks = 0; ks < 4; ++ks) {
        if (rowA < n) {
            a[ks] = *(const half8*)&x[(size_t)rowA * 128 + ks * 32 + khalf * 8];
        } else {
            half8 z = {0, 0, 0, 0, 0, 0, 0, 0};
            a[ks] = z;
        }
    }

    const int crow0 = blockIdx.x * 64 + wave * 16 + khalf * 4;
    float dv[4];
    #pragma unroll
    for (int i = 0; i < 4; ++i) dv[i] = (crow0 + i < n) ? dinv[crow0 + i] : 0.0f;

    _Float16* __restrict__ hsf = (_Float16*)hs;

    #pragma unroll
    for (int ct = 0; ct < OUTC / 16; ++ct) {
        f32x4 acc = {0.f, 0.f, 0.f, 0.f};
        #pragma unroll
        for (int ks = 0; ks < 4; ++ks) {
            half8 b = *(const half8*)&wt[(size_t)(ct * 16 + l15) * 128 + ks * 32 + khalf * 8];
            acc = __builtin_amdgcn_mfma_f32_16x16x32_f16(a[ks], b, acc, 0, 0, 0);
        }
        const int col = ct * 16 + l15;
        #pragma unroll
        for (int i = 0; i < 4; ++i) {
            int r = crow0 + i;
            if (r < n) hsf[(size_t)r * OUTC + col] = (_Float16)(acc[i] * dv[i]);
        }
    }
}

// ---------------- layer-1 aggregate over fp8 hs: sigmoid -> fp16 act ----------------
// 16 threads/node, 8 fp8 cols each (8B uint2 gathers), packed cvt decode.

__device__ inline void fp8x8_add(uint2 r, float* __restrict__ acc) {
    f32x2 f01 = __builtin_amdgcn_cvt_pk_f32_fp8((int)r.x, false);
    f32x2 f23 = __builtin_amdgcn_cvt_pk_f32_fp8((int)r.x, true);
    f32x2 f45 = __builtin_amdgcn_cvt_pk_f32_fp8((int)r.y, false);
    f32x2 f67 = __builtin_amdgcn_cvt_pk_f32_fp8((int)r.y, true);
    acc[0] += f01[0]; acc[1] += f01[1];
    acc[2] += f23[0]; acc[3] += f23[1];
    acc[4] += f45[0]; acc[5] += f45[1];
    acc[6] += f67[0]; acc[7] += f67[1];
}

__global__ void aggregate8_kernel(const int* __restrict__ rowptr, const int* __restrict__ csr_src,
                                  const unsigned char* __restrict__ hs8,
                                  const float* __restrict__ dinv,
                                  const float* __restrict__ bias, __half* __restrict__ out, int n) {
    const int tid  = threadIdx.x;
    const int node = blockIdx.x * 16 + (tid >> 4);
    const int p    = tid & 15;
    if (node >= n) return;

    const unsigned char* __restrict__ hp = hs8 + p * 8;

    float acc[8];
    #pragma unroll
    for (int j = 0; j < 8; ++j) acc[j] = 0.0f;
    fp8x8_add(*(const uint2*)&hp[(size_t)node * 128], acc);   // self-loop

    int e        = rowptr[node];
    const int e1 = rowptr[node + 1];

    for (; e + 8 <= e1; e += 8) {
        int s[8];
        #pragma unroll
        for (int u = 0; u < 8; ++u) s[u] = csr_src[e + u];
        uint2 r[8];
        #pragma unroll
        for (int u = 0; u < 8; ++u) r[u] = *(const uint2*)&hp[(size_t)s[u] * 128];
        #pragma unroll
        for (int u = 0; u < 8; ++u) fp8x8_add(r[u], acc);
    }
    for (; e + 4 <= e1; e += 4) {
        int s[4];
        #pragma unroll
        for (int u = 0; u < 4; ++u) s[u] = csr_src[e + u];
        uint2 r[4];
        #pragma unroll
        for (int u = 0; u < 4; ++u) r[u] = *(const uint2*)&hp[(size_t)s[u] * 128];
        #pragma unroll
        for (int u = 0; u < 4; ++u) fp8x8_add(r[u], acc);
    }
    for (; e < e1; ++e) {
        int s = csr_src[e];
        fp8x8_add(*(const uint2*)&hp[(size_t)s * 128], acc);
    }

    const float sc = dinv[node];
    #pragma unroll
    for (int j = 0; j < 8; ++j) {
        float v = acc[j] * sc + bias[p * 8 + j];
        acc[j] = 1.0f / (1.0f + expf(-v));   // sigmoid (layer 1 only)
    }

    union { __half2 h2[4]; float4 f4; } u;
    #pragma unroll
    for (int j = 0; j < 4; ++j) u.h2[j] = __floats2half2_rn(acc[2 * j], acc[2 * j + 1]);
    *(float4*)&out[(size_t)node * 128 + p * 8] = u.f4;
}

// ---------------- layer-2 aggregate (fp16 hs, fp32 out) ----------------

template <int OUTC, typename OUT_T, bool SIG>
__global__ void aggregate_kernel(const int* __restrict__ rowptr, const int* __restrict__ csr_src,
                                 const __half* __restrict__ hs, const float* __restrict__ dinv,
                                 const float* __restrict__ bias, OUT_T* __restrict__ out, int n) {
    constexpr int CPT = 8;
    constexpr int TPR = OUTC / CPT;
    constexpr int NPB = 256 / TPR;
    const int tid  = threadIdx.x;
    const int node = blockIdx.x * NPB + tid / TPR;
    const int p    = tid % TPR;
    if (node >= n) return;

    const __half* __restrict__ hp = hs + (size_t)p * CPT;

    float acc[CPT];
    {
        float4 raw = *(const float4*)&hp[(size_t)node * OUTC];
        const __half2* h2 = (const __half2*)&raw;
        #pragma unroll
        for (int j = 0; j < 4; ++j) {
            float2 f = __half22float2(h2[j]);
            acc[2 * j] = f.x; acc[2 * j + 1] = f.y;
        }
    }

    int e        = rowptr[node];
    const int e1 = rowptr[node + 1];

    for (; e + 8 <= e1; e += 8) {
        int s[8];
        #pragma unroll
        for (int u = 0; u < 8; ++u) s[u] = csr_src[e + u];
        float4 r[8];
        #pragma unroll
        for (int u = 0; u < 8; ++u) r[u] = *(const float4*)&hp[(size_t)s[u] * OUTC];
        #pragma unroll
        for (int j = 0; j < 4; ++j) {
            #pragma unroll
            for (int u = 0; u < 8; ++u) {
                float2 f = __half22float2(((const __half2*)&r[u])[j]);
                acc[2 * j] += f.x; acc[2 * j + 1] += f.y;
            }
        }
    }
    for (; e + 4 <= e1; e += 4) {
        int s[4];
        #pragma unroll
        for (int u = 0; u < 4; ++u) s[u] = csr_src[e + u];
        float4 r[4];
        #pragma unroll
        for (int u = 0; u < 4; ++u) r[u] = *(const float4*)&hp[(size_t)s[u] * OUTC];
        #pragma unroll
        for (int j = 0; j < 4; ++j) {
            #pragma unroll
            for (int u = 0; u < 4; ++u) {
                float2 f = __half22float2(((const __half2*)&r[u])[j]);
                acc[2 * j] += f.x; acc[2 * j + 1] += f.y;
            }
        }
    }
    for (; e < e1; ++e) {
        int s = csr_src[e];
        float4 r = *(const float4*)&hp[(size_t)s * OUTC];
        const __half2* a = (const __half2*)&r;
        #pragma unroll
        for (int j = 0; j < 4; ++j) {
            float2 f = __half22float2(a[j]);
            acc[2 * j] += f.x; acc[2 * j + 1] += f.y;
        }
    }

    const float sc = dinv[node];
    #pragma unroll
    for (int j = 0; j < CPT; ++j) {
        float v = acc[j] * sc + bias[p * CPT + j];
        if (SIG) v = 1.0f / (1.0f + expf(-v));
        acc[j] = v;
    }

    if constexpr (sizeof(OUT_T) == 2) {
        union { __half2 h2[4]; float4 f4; } u;
        u.h2[0] = __floats2half2_rn(acc[0], acc[1]);
        u.h2[1] = __floats2half2_rn(acc[2], acc[3]);
        u.h2[2] = __floats2half2_rn(acc[4], acc[5]);
        u.h2[3] = __floats2half2_rn(acc[6], acc[7]);
        *(float4*)&out[(size_t)node * OUTC + p * CPT] = u.f4;
    } else {
        float* o = (float*)&out[(size_t)node * OUTC + p * CPT];
        *(float4*)&o[0] = make_float4(acc[0], acc[1], acc[2], acc[3]);
        *(float4*)&o[4] = make_float4(acc[4], acc[5], acc[6], acc[7]);
    }
}

static inline size_t align256(size_t x) { return (x + 255) & ~size_t(255); }

extern "C" void kernel_launch(void* const* d_in, const int* in_sizes, int n_in,
                              void* d_out, int out_size, void* d_ws, size_t ws_size,
                              hipStream_t stream) {
    const float* x   = (const float*)d_in[0];
    const int*   e32 = (const int*)d_in[1];   // [2,E] int32
    const float* W0  = (const float*)d_in[2];
    const float* b0  = (const float*)d_in[3];
    const float* W1  = (const float*)d_in[4];
    const float* b1  = (const float*)d_in[5];
    float* out = (float*)d_out;

    const int N = in_sizes[0] / 128;   // 50000
    const int E = in_sizes[1] / 2;     // 800000
    const int* src = e32;
    const int* dst = e32 + E;

    // Workspace layout
    char* p = (char*)d_ws;
    int*           deg     = (int*)p;           p += align256((size_t)N * 4);
    float*         dinv    = (float*)p;         p += align256((size_t)N * 4);
    int*           rowptr  = (int*)p;           p += align256((size_t)(N + 1) * 4);
    int*           rank    = (int*)p;           p += align256((size_t)E * 4);
    int*           bsum    = (int*)p;           p += align256((size_t)256 * 4);
    int*           csr_src = (int*)p;           p += align256((size_t)E * 4);
    unsigned char* hs8     = (unsigned char*)p; p += align256((size_t)N * 128);      // fp8 layer-1 hs
    __half*        hs      = (__half*)p;        p += align256((size_t)N * 64 * 2);   // fp16 layer-2 hs
    __half*        act     = (__half*)p;        p += align256((size_t)N * 128 * 2);  // fp16 inter-layer
    __half*        wt0     = (__half*)p;        p += align256((size_t)128 * 128 * 2);
    __half*        wt1     = (__half*)p;        p += align256((size_t)64 * 128 * 2);

    const int nb = (N + 1023) / 1024;     // 49 scan blocks (<= 64)
    const int n4 = (N + 3) / 4;

    // ---- init (zero deg + weight convert), then CSR build ----
    init_kernel<<<(n4 + 128 * 128 + 64 * 128 + BLK - 1) / BLK, BLK, 0, stream>>>(
        (int4*)deg, n4, W0, W1, wt0, wt1);
    const int e4 = (E + 3) / 4;
    deg_rank_kernel<<<(e4 + BLK - 1) / BLK, BLK, 0, stream>>>(dst, deg, rank, E);
    scan1_kernel<<<nb, BLK, 0, stream>>>(deg, rowptr, bsum, dinv, N);
    scan23_kernel<<<(N + BLK - 1) / BLK, BLK, 0, stream>>>(rowptr, bsum, N, E, nb);

    const int ggrid = (N + 63) / 64;
    const int fgrid = (e4 + BLK - 1) / BLK;

    // ---- fused CSR fill (4 edges/thread) + layer-1 GEMM (fp8 hs out) ----
    fill_gemm1_kernel<<<ggrid + fgrid, BLK, 0, stream>>>(
        src, dst, rank, rowptr, csr_src, E, x, wt0, dinv, hs8, N, ggrid);

    // ---- Layer 1 aggregate: fp8 gather, sigmoid, fp16 act ----
    aggregate8_kernel<<<(N + 15) / 16, BLK, 0, stream>>>(
        rowptr, csr_src, hs8, dinv, b0, act, N);

    // ---- Layer 2: 128 -> 64, fp16 path, no activation ----
    gemm_mfma_kernel<64><<<ggrid, BLK, 0, stream>>>(act, wt1, dinv, hs, N);
    aggregate_kernel<64, float, false><<<(N + 31) / 32, BLK, 0, stream>>>(
        rowptr, csr_src, hs, dinv, b1, out, N);
}

// Round 16
// 110.863 us; speedup vs baseline: 1.2040x; 1.2040x over previous
//
#include <hip/hip_runtime.h>
#include <hip/hip_fp16.h>
#include <math.h>

#define BLK 256

typedef _Float16 half8 __attribute__((ext_vector_type(8)));
typedef float f32x4 __attribute__((ext_vector_type(4)));
typedef float f32x2 __attribute__((ext_vector_type(2)));

// ---------------- init: convert/transpose weights (no zeroing needed anywhere) ----------------
__global__ void init_kernel(const float* __restrict__ W0, const float* __restrict__ W1,
                            __half* __restrict__ wt0, __half* __restrict__ wt1) {
    int u = blockIdx.x * blockDim.x + threadIdx.x;
    if (u < 128 * 128) {
        int c = u >> 7, k = u & 127;
        wt0[u] = __float2half(W0[k * 128 + c]);
    } else if (u < 128 * 128 + 64 * 128) {
        int v = u - 128 * 128;
        int c = v >> 7, k = v & 127;
        wt1[v] = __float2half(W1[k * 64 + c]);
    }
}

// ---------------- S1: per-chunk bucket histogram (LDS only; plain stores) ----------------
// chunk = 1024 edges; bucket = dst>>8 (nbkt = ceil(N/256) <= 256).
__global__ void count_kernel(const int* __restrict__ dst, int* __restrict__ countmat,
                             int E, int nbkt) {
    __shared__ int h[256];
    int tid = threadIdx.x;
    h[tid] = 0;
    __syncthreads();
    int e0 = blockIdx.x * 1024;
    int lim = min(e0 + 1024, E);
    for (int e = e0 + tid; e < lim; e += 256) atomicAdd(&h[dst[e] >> 8], 1);
    __syncthreads();
    if (tid < nbkt) countmat[(size_t)blockIdx.x * nbkt + tid] = h[tid];
}

// ---------------- S2: per-bucket exclusive scan over chunk-blocks (grid = nbkt) ----------------
// countmat[i][b] -> exclusive prefix over i; total[b] = column sum. CB <= 1024.
__global__ void colscan_kernel(int* __restrict__ countmat, int* __restrict__ total,
                               int CB, int nbkt) {
    __shared__ int s[BLK];
    int b = blockIdx.x, tid = threadIdx.x;
    int v[4];
    int sum = 0;
    #pragma unroll
    for (int j = 0; j < 4; ++j) {
        int i = tid * 4 + j;
        v[j] = (i < CB) ? countmat[(size_t)i * nbkt + b] : 0;
        sum += v[j];
    }
    s[tid] = sum;
    __syncthreads();
    #pragma unroll
    for (int off = 1; off < BLK; off <<= 1) {
        int t = 0;
        if (tid >= off) t = s[tid - off];
        __syncthreads();
        if (tid >= off) s[tid] += t;
        __syncthreads();
    }
    int run = s[tid] - sum;
    #pragma unroll
    for (int j = 0; j < 4; ++j) {
        int i = tid * 4 + j;
        if (i < CB) countmat[(size_t)i * nbkt + b] = run;
        run += v[j];
    }
    if (tid == BLK - 1) total[b] = s[BLK - 1];
}

// ---------------- S3: scatter edges into bucket-major order (LDS atomics only) ----------------
__global__ void scatter_kernel(const int* __restrict__ dst, const int* __restrict__ src,
                               const int* __restrict__ countmat, const int* __restrict__ total,
                               int2* __restrict__ sorted, int* __restrict__ bbase,
                               int E, int nbkt) {
    __shared__ int s[BLK];
    __shared__ int base[256];
    __shared__ int h[256];
    int tid = threadIdx.x;
    int tv = (tid < nbkt) ? total[tid] : 0;
    s[tid] = tv;
    __syncthreads();
    #pragma unroll
    for (int off = 1; off < BLK; off <<= 1) {
        int t = 0;
        if (tid >= off) t = s[tid - off];
        __syncthreads();
        if (tid >= off) s[tid] += t;
        __syncthreads();
    }
    base[tid] = s[tid] - tv;   // exclusive bucket base in edge space
    h[tid] = 0;
    __syncthreads();
    if (blockIdx.x == 0) {
        if (tid < nbkt) bbase[tid] = base[tid];
        if (tid == 0) bbase[nbkt] = E;
    }
    int e0 = blockIdx.x * 1024;
    int lim = min(e0 + 1024, E);
    const int* myoff = countmat + (size_t)blockIdx.x * nbkt;
    for (int e = e0 + tid; e < lim; e += 256) {
        int d = dst[e];
        int sv = src[e];
        int b = d >> 8;
        int lr = atomicAdd(&h[b], 1);            // LDS
        int pos = base[b] + myoff[b] + lr;
        sorted[pos] = make_int2(d, sv);
    }
}

// ---------------- S4: per-bucket CSR finalize: rowptr/deg/dinv + csr_src (LDS only) ----------------
__global__ void csr_kernel(const int2* __restrict__ sorted, const int* __restrict__ bbase,
                           int* __restrict__ rowptr, float* __restrict__ dinv,
                           int* __restrict__ csr_src, int N, int E) {
    __shared__ int h[256];
    __shared__ int s[BLK];
    __shared__ int cur[256];
    int b = blockIdx.x, tid = threadIdx.x;
    int eb0 = bbase[b], eb1 = bbase[b + 1];
    h[tid] = 0;
    __syncthreads();
    for (int e = eb0 + tid; e < eb1; e += 256) atomicAdd(&h[sorted[e].x & 255], 1);
    __syncthreads();
    int hv = h[tid];
    s[tid] = hv;
    __syncthreads();
    #pragma unroll
    for (int off = 1; off < BLK; off <<= 1) {
        int t = 0;
        if (tid >= off) t = s[tid - off];
        __syncthreads();
        if (tid >= off) s[tid] += t;
        __syncthreads();
    }
    int sc = s[tid] - hv;   // exclusive within bucket
    int node = b * 256 + tid;
    if (node < N) {
        rowptr[node] = eb0 + sc;
        dinv[node] = rsqrtf((float)(hv + 1));
    }
    cur[tid] = sc;
    if (b == 0 && tid == 0) rowptr[N] = E;
    __syncthreads();
    for (int e = eb0 + tid; e < eb1; e += 256) {
        int2 p = sorted[e];
        int lr = atomicAdd(&cur[p.x & 255], 1);  // LDS
        csr_src[eb0 + lr] = p.y;
    }
}

// ---------------- MFMA GEMM layer 1: hs8 = fp8((x @ W0) * dinv[row]) ----------------

__global__ __launch_bounds__(256) void gemm1_kernel(const float* __restrict__ x,
                                                    const __half* __restrict__ wt,
                                                    const float* __restrict__ dinv,
                                                    unsigned char* __restrict__ hs8, int n) {
    const int tid   = threadIdx.x;
    const int wave  = tid >> 6;
    const int lane  = tid & 63;
    const int l15   = lane & 15;
    const int khalf = lane >> 4;

    const int rowA = blockIdx.x * 64 + wave * 16 + l15;

    half8 a[4];
    #pragma unroll
    for (int ks = 0; ks < 4; ++ks) {
        if (rowA < n) {
            const float* px = &x[(size_t)rowA * 128 + ks * 32 + khalf * 8];
            float4 f0 = *(const float4*)&px[0];
            float4 f1 = *(const float4*)&px[4];
            union { half8 h8; __half2 h2[4]; } u;
            u.h2[0] = __floats2half2_rn(f0.x, f0.y);
            u.h2[1] = __floats2half2_rn(f0.z, f0.w);
            u.h2[2] = __floats2half2_rn(f1.x, f1.y);
            u.h2[3] = __floats2half2_rn(f1.z, f1.w);
            a[ks] = u.h8;
        } else {
            half8 z = {0, 0, 0, 0, 0, 0, 0, 0};
            a[ks] = z;
        }
    }

    const int crow0 = blockIdx.x * 64 + wave * 16 + khalf * 4;
    float dv[4];
    #pragma unroll
    for (int i = 0; i < 4; ++i) dv[i] = (crow0 + i < n) ? dinv[crow0 + i] : 0.0f;

    #pragma unroll
    for (int ct = 0; ct < 8; ++ct) {          // OUTC = 128
        f32x4 acc = {0.f, 0.f, 0.f, 0.f};
        #pragma unroll
        for (int ks = 0; ks < 4; ++ks) {
            half8 b = *(const half8*)&wt[(size_t)(ct * 16 + l15) * 128 + ks * 32 + khalf * 8];
            acc = __builtin_amdgcn_mfma_f32_16x16x32_f16(a[ks], b, acc, 0, 0, 0);
        }
        const int col = ct * 16 + l15;
        #pragma unroll
        for (int i = 0; i < 4; ++i) {
            int r = crow0 + i;
            if (r < n) {
                float f = acc[i] * dv[i];
                unsigned int b8 = (unsigned int)__builtin_amdgcn_cvt_pk_fp8_f32(f, f, 0, 0);
                hs8[(size_t)r * 128 + col] = (unsigned char)(b8 & 0xff);
            }
        }
    }
}

// ---------------- MFMA GEMM layer 2 (fp16 input, fp16 output) ----------------

template <int OUTC>
__global__ __launch_bounds__(256) void gemm_mfma_kernel(const __half* __restrict__ x,
                                                        const __half* __restrict__ wt,
                                                        const float* __restrict__ dinv,
                                                        __half* __restrict__ hs, int n) {
    const int tid   = threadIdx.x;
    const int wave  = tid >> 6;
    const int lane  = tid & 63;
    const int l15   = lane & 15;
    const int khalf = lane >> 4;

    const int rowA = blockIdx.x * 64 + wave * 16 + l15;

    half8 a[4];
    #pragma unroll
    for (int ks = 0; ks < 4; ++ks) {
        if (rowA < n) {
            a[ks] = *(const half8*)&x[(size_t)rowA * 128 + ks * 32 + khalf * 8];
        } else {
            half8 z = {0, 0, 0, 0, 0, 0, 0, 0};
            a[ks] = z;
        }
    }

    const int crow0 = blockIdx.x * 64 + wave * 16 + khalf * 4;
    float dv[4];
    #pragma unroll
    for (int i = 0; i < 4; ++i) dv[i] = (crow0 + i < n) ? dinv[crow0 + i] : 0.0f;

    _Float16* __restrict__ hsf = (_Float16*)hs;

    #pragma unroll
    for (int ct = 0; ct < OUTC / 16; ++ct) {
        f32x4 acc = {0.f, 0.f, 0.f, 0.f};
        #pragma unroll
        for (int ks = 0; ks < 4; ++ks) {
            half8 b = *(const half8*)&wt[(size_t)(ct * 16 + l15) * 128 + ks * 32 + khalf * 8];
            acc = __builtin_amdgcn_mfma_f32_16x16x32_f16(a[ks], b, acc, 0, 0, 0);
        }
        const int col = ct * 16 + l15;
        #pragma unroll
        for (int i = 0; i < 4; ++i) {
            int r = crow0 + i;
            if (r < n) hsf[(size_t)r * OUTC + col] = (_Float16)(acc[i] * dv[i]);
        }
    }
}

// ---------------- layer-1 aggregate over fp8 hs: sigmoid -> fp16 act ----------------
// 16 threads/node, 8 fp8 cols each (8B uint2 gathers), packed cvt decode.

__device__ inline void fp8x8_add(uint2 r, float* __restrict__ acc) {
    f32x2 f01 = __builtin_amdgcn_cvt_pk_f32_fp8((int)r.x, false);
    f32x2 f23 = __builtin_amdgcn_cvt_pk_f32_fp8((int)r.x, true);
    f32x2 f45 = __builtin_amdgcn_cvt_pk_f32_fp8((int)r.y, false);
    f32x2 f67 = __builtin_amdgcn_cvt_pk_f32_fp8((int)r.y, true);
    acc[0] += f01[0]; acc[1] += f01[1];
    acc[2] += f23[0]; acc[3] += f23[1];
    acc[4] += f45[0]; acc[5] += f45[1];
    acc[6] += f67[0]; acc[7] += f67[1];
}

__global__ void aggregate8_kernel(const int* __restrict__ rowptr, const int* __restrict__ csr_src,
                                  const unsigned char* __restrict__ hs8,
                                  const float* __restrict__ dinv,
                                  const float* __restrict__ bias, __half* __restrict__ out, int n) {
    const int tid  = threadIdx.x;
    const int node = blockIdx.x * 16 + (tid >> 4);
    const int p    = tid & 15;
    if (node >= n) return;

    const unsigned char* __restrict__ hp = hs8 + p * 8;

    float acc[8];
    #pragma unroll
    for (int j = 0; j < 8; ++j) acc[j] = 0.0f;
    fp8x8_add(*(const uint2*)&hp[(size_t)node * 128], acc);   // self-loop

    int e        = rowptr[node];
    const int e1 = rowptr[node + 1];

    for (; e + 8 <= e1; e += 8) {
        int s[8];
        #pragma unroll
        for (int u = 0; u < 8; ++u) s[u] = csr_src[e + u];
        uint2 r[8];
        #pragma unroll
        for (int u = 0; u < 8; ++u) r[u] = *(const uint2*)&hp[(size_t)s[u] * 128];
        #pragma unroll
        for (int u = 0; u < 8; ++u) fp8x8_add(r[u], acc);
    }
    for (; e + 4 <= e1; e += 4) {
        int s[4];
        #pragma unroll
        for (int u = 0; u < 4; ++u) s[u] = csr_src[e + u];
        uint2 r[4];
        #pragma unroll
        for (int u = 0; u < 4; ++u) r[u] = *(const uint2*)&hp[(size_t)s[u] * 128];
        #pragma unroll
        for (int u = 0; u < 4; ++u) fp8x8_add(r[u], acc);
    }
    for (; e < e1; ++e) {
        int s = csr_src[e];
        fp8x8_add(*(const uint2*)&hp[(size_t)s * 128], acc);
    }

    const float sc = dinv[node];
    #pragma unroll
    for (int j = 0; j < 8; ++j) {
        float v = acc[j] * sc + bias[p * 8 + j];
        acc[j] = 1.0f / (1.0f + expf(-v));   // sigmoid (layer 1 only)
    }

    union { __half2 h2[4]; float4 f4; } u;
    #pragma unroll
    for (int j = 0; j < 4; ++j) u.h2[j] = __floats2half2_rn(acc[2 * j], acc[2 * j + 1]);
    *(float4*)&out[(size_t)node * 128 + p * 8] = u.f4;
}

// ---------------- layer-2 aggregate (fp16 hs, fp32 out) ----------------

template <int OUTC, typename OUT_T, bool SIG>
__global__ void aggregate_kernel(const int* __restrict__ rowptr, const int* __restrict__ csr_src,
                                 const __half* __restrict__ hs, const float* __restrict__ dinv,
                                 const float* __restrict__ bias, OUT_T* __restrict__ out, int n) {
    constexpr int CPT = 8;
    constexpr int TPR = OUTC / CPT;
    constexpr int NPB = 256 / TPR;
    const int tid  = threadIdx.x;
    const int node = blockIdx.x * NPB + tid / TPR;
    const int p    = tid % TPR;
    if (node >= n) return;

    const __half* __restrict__ hp = hs + (size_t)p * CPT;

    float acc[CPT];
    {
        float4 raw = *(const float4*)&hp[(size_t)node * OUTC];
        const __half2* h2 = (const __half2*)&raw;
        #pragma unroll
        for (int j = 0; j < 4; ++j) {
            float2 f = __half22float2(h2[j]);
            acc[2 * j] = f.x; acc[2 * j + 1] = f.y;
        }
    }

    int e        = rowptr[node];
    const int e1 = rowptr[node + 1];

    for (; e + 8 <= e1; e += 8) {
        int s[8];
        #pragma unroll
        for (int u = 0; u < 8; ++u) s[u] = csr_src[e + u];
        float4 r[8];
        #pragma unroll
        for (int u = 0; u < 8; ++u) r[u] = *(const float4*)&hp[(size_t)s[u] * OUTC];
        #pragma unroll
        for (int j = 0; j < 4; ++j) {
            #pragma unroll
            for (int u = 0; u < 8; ++u) {
                float2 f = __half22float2(((const __half2*)&r[u])[j]);
                acc[2 * j] += f.x; acc[2 * j + 1] += f.y;
            }
        }
    }
    for (; e + 4 <= e1; e += 4) {
        int s[4];
        #pragma unroll
        for (int u = 0; u < 4; ++u) s[u] = csr_src[e + u];
        float4 r[4];
        #pragma unroll
        for (int u = 0; u < 4; ++u) r[u] = *(const float4*)&hp[(size_t)s[u] * OUTC];
        #pragma unroll
        for (int j = 0; j < 4; ++j) {
            #pragma unroll
            for (int u = 0; u < 4; ++u) {
                float2 f = __half22float2(((const __half2*)&r[u])[j]);
                acc[2 * j] += f.x; acc[2 * j + 1] += f.y;
            }
        }
    }
    for (; e < e1; ++e) {
        int s = csr_src[e];
        float4 r = *(const float4*)&hp[(size_t)s * OUTC];
        const __half2* a = (const __half2*)&r;
        #pragma unroll
        for (int j = 0; j < 4; ++j) {
            float2 f = __half22float2(a[j]);
            acc[2 * j] += f.x; acc[2 * j + 1] += f.y;
        }
    }

    const float sc = dinv[node];
    #pragma unroll
    for (int j = 0; j < CPT; ++j) {
        float v = acc[j] * sc + bias[p * CPT + j];
        if (SIG) v = 1.0f / (1.0f + expf(-v));
        acc[j] = v;
    }

    if constexpr (sizeof(OUT_T) == 2) {
        union { __half2 h2[4]; float4 f4; } u;
        u.h2[0] = __floats2half2_rn(acc[0], acc[1]);
        u.h2[1] = __floats2half2_rn(acc[2], acc[3]);
        u.h2[2] = __floats2half2_rn(acc[4], acc[5]);
        u.h2[3] = __floats2half2_rn(acc[6], acc[7]);
        *(float4*)&out[(size_t)node * OUTC + p * CPT] = u.f4;
    } else {
        float* o = (float*)&out[(size_t)node * OUTC + p * CPT];
        *(float4*)&o[0] = make_float4(acc[0], acc[1], acc[2], acc[3]);
        *(float4*)&o[4] = make_float4(acc[4], acc[5], acc[6], acc[7]);
    }
}

static inline size_t align256(size_t x) { return (x + 255) & ~size_t(255); }

extern "C" void kernel_launch(void* const* d_in, const int* in_sizes, int n_in,
                              void* d_out, int out_size, void* d_ws, size_t ws_size,
                              hipStream_t stream) {
    const float* x   = (const float*)d_in[0];
    const int*   e32 = (const int*)d_in[1];   // [2,E] int32
    const float* W0  = (const float*)d_in[2];
    const float* b0  = (const float*)d_in[3];
    const float* W1  = (const float*)d_in[4];
    const float* b1  = (const float*)d_in[5];
    float* out = (float*)d_out;

    const int N = in_sizes[0] / 128;   // 50000
    const int E = in_sizes[1] / 2;     // 800000
    const int* src = e32;
    const int* dst = e32 + E;

    const int nbkt = (N + 255) >> 8;          // 196 (requires N <= 65536)
    const int CB   = (E + 1023) >> 10;        // 782 chunk-blocks (requires CB <= 1024)

    // Workspace layout
    char* p = (char*)d_ws;
    int*           countmat = (int*)p;           p += align256((size_t)CB * nbkt * 4);
    int*           total    = (int*)p;           p += align256((size_t)256 * 4);
    int*           bbase    = (int*)p;           p += align256((size_t)(nbkt + 1) * 4);
    int2*          sorted   = (int2*)p;          p += align256((size_t)E * 8);
    int*           rowptr   = (int*)p;           p += align256((size_t)(N + 1) * 4);
    float*         dinv     = (float*)p;         p += align256((size_t)N * 4);
    int*           csr_src  = (int*)p;           p += align256((size_t)E * 4);
    unsigned char* hs8      = (unsigned char*)p; p += align256((size_t)N * 128);      // fp8 layer-1 hs
    __half*        hs       = (__half*)p;        p += align256((size_t)N * 64 * 2);   // fp16 layer-2 hs
    __half*        act      = (__half*)p;        p += align256((size_t)N * 128 * 2);  // fp16 inter-layer
    __half*        wt0      = (__half*)p;        p += align256((size_t)128 * 128 * 2);
    __half*        wt1      = (__half*)p;        p += align256((size_t)64 * 128 * 2);

    // ---- weight convert (independent) ----
    init_kernel<<<(128 * 128 + 64 * 128 + BLK - 1) / BLK, BLK, 0, stream>>>(W0, W1, wt0, wt1);

    // ---- atomic-free CSR build via bucket sort ----
    count_kernel<<<CB, BLK, 0, stream>>>(dst, countmat, E, nbkt);
    colscan_kernel<<<nbkt, BLK, 0, stream>>>(countmat, total, CB, nbkt);
    scatter_kernel<<<CB, BLK, 0, stream>>>(dst, src, countmat, total, sorted, bbase, E, nbkt);
    csr_kernel<<<nbkt, BLK, 0, stream>>>(sorted, bbase, rowptr, dinv, csr_src, N, E);

    const int ggrid = (N + 63) / 64;

    // ---- Layer 1: GEMM (fp8 hs) + aggregate (fp8 gather, sigmoid, fp16 act) ----
    gemm1_kernel<<<ggrid, BLK, 0, stream>>>(x, wt0, dinv, hs8, N);
    aggregate8_kernel<<<(N + 15) / 16, BLK, 0, stream>>>(
        rowptr, csr_src, hs8, dinv, b0, act, N);

    // ---- Layer 2: 128 -> 64, fp16 path, no activation ----
    gemm_mfma_kernel<64><<<ggrid, BLK, 0, stream>>>(act, wt1, dinv, hs, N);
    aggregate_kernel<64, float, false><<<(N + 31) / 32, BLK, 0, stream>>>(
        rowptr, csr_src, hs, dinv, b1, out, N);
}

// Round 17
// 97.177 us; speedup vs baseline: 1.3735x; 1.1408x over previous
//
#include <hip/hip_runtime.h>
#include <hip/hip_fp16.h>
#include <math.h>

#define BLK 256

typedef _Float16 half8 __attribute__((ext_vector_type(8)));
typedef float f32x4 __attribute__((ext_vector_type(4)));
typedef float f32x2 __attribute__((ext_vector_type(2)));

// ---------------- K1: per-chunk bucket histogram + weight convert (block-split) ----------------
// Blocks [0,CB): chunk histograms (chunk = 1024 edges, bucket = dst>>8).
// Blocks [CB, CB+96): wt[c][k] = fp16(W[k][c]).
__global__ void count_init_kernel(const int* __restrict__ dst, int* __restrict__ countmat,
                                  int E, int nbkt, int CB,
                                  const float* __restrict__ W0, const float* __restrict__ W1,
                                  __half* __restrict__ wt0, __half* __restrict__ wt1) {
    __shared__ int h[256];
    int bid = blockIdx.x, tid = threadIdx.x;
    if (bid < CB) {
        h[tid] = 0;
        __syncthreads();
        int e0 = bid * 1024;
        int lim = min(e0 + 1024, E);
        for (int e = e0 + tid; e < lim; e += 256) atomicAdd(&h[dst[e] >> 8], 1);
        __syncthreads();
        if (tid < nbkt) countmat[(size_t)bid * nbkt + tid] = h[tid];
    } else {
        int u = (bid - CB) * 256 + tid;
        if (u < 128 * 128) {
            int c = u >> 7, k = u & 127;
            wt0[u] = __float2half(W0[k * 128 + c]);
        } else if (u < 128 * 128 + 64 * 128) {
            int v = u - 128 * 128;
            int c = v >> 7, k = v & 127;
            wt1[v] = __float2half(W1[k * 64 + c]);
        }
    }
}

// ---------------- K2: per-bucket exclusive scan over chunk-blocks (grid = nbkt) ----------------
__global__ void colscan_kernel(int* __restrict__ countmat, int* __restrict__ total,
                               int CB, int nbkt) {
    __shared__ int s[BLK];
    int b = blockIdx.x, tid = threadIdx.x;
    int v[4];
    int sum = 0;
    #pragma unroll
    for (int j = 0; j < 4; ++j) {
        int i = tid * 4 + j;
        v[j] = (i < CB) ? countmat[(size_t)i * nbkt + b] : 0;
        sum += v[j];
    }
    s[tid] = sum;
    __syncthreads();
    #pragma unroll
    for (int off = 1; off < BLK; off <<= 1) {
        int t = 0;
        if (tid >= off) t = s[tid - off];
        __syncthreads();
        if (tid >= off) s[tid] += t;
        __syncthreads();
    }
    int run = s[tid] - sum;
    #pragma unroll
    for (int j = 0; j < 4; ++j) {
        int i = tid * 4 + j;
        if (i < CB) countmat[(size_t)i * nbkt + b] = run;
        run += v[j];
    }
    if (tid == BLK - 1) total[b] = s[BLK - 1];
}

// ---------------- K3: scatter edges into bucket-major order, PACKED uint32 ----------------
// word = (dst&255)<<24 | src  (src < 2^24). LDS atomics only.
__global__ void scatter_kernel(const int* __restrict__ dst, const int* __restrict__ src,
                               const int* __restrict__ countmat, const int* __restrict__ total,
                               unsigned* __restrict__ sorted, int* __restrict__ bbase,
                               int E, int nbkt) {
    __shared__ int s[BLK];
    __shared__ int base[256];
    __shared__ int h[256];
    int tid = threadIdx.x;
    int tv = (tid < nbkt) ? total[tid] : 0;
    s[tid] = tv;
    __syncthreads();
    #pragma unroll
    for (int off = 1; off < BLK; off <<= 1) {
        int t = 0;
        if (tid >= off) t = s[tid - off];
        __syncthreads();
        if (tid >= off) s[tid] += t;
        __syncthreads();
    }
    base[tid] = s[tid] - tv;
    h[tid] = 0;
    __syncthreads();
    if (blockIdx.x == 0) {
        if (tid < nbkt) bbase[tid] = base[tid];
        if (tid == 0) bbase[nbkt] = E;
    }
    int e0 = blockIdx.x * 1024;
    int lim = min(e0 + 1024, E);
    const int* myoff = countmat + (size_t)blockIdx.x * nbkt;
    for (int e = e0 + tid; e < lim; e += 256) {
        int d = dst[e];
        unsigned w = ((unsigned)(d & 255) << 24) | (unsigned)src[e];
        int b = d >> 8;
        int lr = atomicAdd(&h[b], 1);            // LDS
        sorted[base[b] + myoff[b] + lr] = w;
    }
}

// ---------------- K4: per-bucket CSR finalize + layer-1 MFMA GEMM for the bucket's rows ----------------
__global__ __launch_bounds__(256) void csr_gemm1_kernel(
    const unsigned* __restrict__ sorted, const int* __restrict__ bbase,
    int* __restrict__ rowptr, float* __restrict__ dinv, int* __restrict__ csr_src,
    int N, int E,
    const float* __restrict__ x, const __half* __restrict__ wt0,
    unsigned char* __restrict__ hs8) {
    __shared__ int h[256];
    __shared__ int s[BLK];
    __shared__ int cur[256];
    __shared__ float dinv_lds[256];
    int b = blockIdx.x, tid = threadIdx.x;
    int eb0 = bbase[b], eb1 = bbase[b + 1];
    h[tid] = 0;
    __syncthreads();
    for (int e = eb0 + tid; e < eb1; e += 256) atomicAdd(&h[sorted[e] >> 24], 1);
    __syncthreads();
    int hv = h[tid];
    s[tid] = hv;
    __syncthreads();
    #pragma unroll
    for (int off = 1; off < BLK; off <<= 1) {
        int t = 0;
        if (tid >= off) t = s[tid - off];
        __syncthreads();
        if (tid >= off) s[tid] += t;
        __syncthreads();
    }
    int sc = s[tid] - hv;   // exclusive within bucket
    int node = b * 256 + tid;
    float dv = rsqrtf((float)(hv + 1));
    dinv_lds[tid] = dv;
    if (node < N) {
        rowptr[node] = eb0 + sc;
        dinv[node] = dv;
    }
    cur[tid] = sc;
    if (b == 0 && tid == 0) rowptr[N] = E;
    __syncthreads();
    for (int e = eb0 + tid; e < eb1; e += 256) {
        unsigned w = sorted[e];
        int lr = atomicAdd(&cur[w >> 24], 1);    // LDS
        csr_src[eb0 + lr] = (int)(w & 0xFFFFFFu);
    }
    __syncthreads();

    // ---- gemm1 for rows [b*256, b*256+256): hs8 = fp8((x @ W0) * dinv) ----
    const int wave  = tid >> 6;
    const int lane  = tid & 63;
    const int l15   = lane & 15;
    const int khalf = lane >> 4;

    for (int sub = 0; sub < 4; ++sub) {
        const int rowA = b * 256 + sub * 64 + wave * 16 + l15;
        half8 a[4];
        #pragma unroll
        for (int ks = 0; ks < 4; ++ks) {
            if (rowA < N) {
                const float* px = &x[(size_t)rowA * 128 + ks * 32 + khalf * 8];
                float4 f0 = *(const float4*)&px[0];
                float4 f1 = *(const float4*)&px[4];
                union { half8 h8; __half2 h2[4]; } u;
                u.h2[0] = __floats2half2_rn(f0.x, f0.y);
                u.h2[1] = __floats2half2_rn(f0.z, f0.w);
                u.h2[2] = __floats2half2_rn(f1.x, f1.y);
                u.h2[3] = __floats2half2_rn(f1.z, f1.w);
                a[ks] = u.h8;
            } else {
                half8 z = {0, 0, 0, 0, 0, 0, 0, 0};
                a[ks] = z;
            }
        }
        const int lrow0 = sub * 64 + wave * 16 + khalf * 4;
        #pragma unroll
        for (int ct = 0; ct < 8; ++ct) {
            f32x4 acc = {0.f, 0.f, 0.f, 0.f};
            #pragma unroll
            for (int ks = 0; ks < 4; ++ks) {
                half8 bb = *(const half8*)&wt0[(size_t)(ct * 16 + l15) * 128 + ks * 32 + khalf * 8];
                acc = __builtin_amdgcn_mfma_f32_16x16x32_f16(a[ks], bb, acc, 0, 0, 0);
            }
            const int col = ct * 16 + l15;
            #pragma unroll
            for (int i = 0; i < 4; ++i) {
                int r = b * 256 + lrow0 + i;
                if (r < N) {
                    float f = acc[i] * dinv_lds[lrow0 + i];
                    unsigned int b8 = (unsigned int)__builtin_amdgcn_cvt_pk_fp8_f32(f, f, 0, 0);
                    hs8[(size_t)r * 128 + col] = (unsigned char)(b8 & 0xff);
                }
            }
        }
    }
}

// ---------------- fp8 decode helper (packed, word-sel literal) ----------------
__device__ inline void fp8x8_add(uint2 r, float* __restrict__ acc) {
    f32x2 f01 = __builtin_amdgcn_cvt_pk_f32_fp8((int)r.x, false);
    f32x2 f23 = __builtin_amdgcn_cvt_pk_f32_fp8((int)r.x, true);
    f32x2 f45 = __builtin_amdgcn_cvt_pk_f32_fp8((int)r.y, false);
    f32x2 f67 = __builtin_amdgcn_cvt_pk_f32_fp8((int)r.y, true);
    acc[0] += f01[0]; acc[1] += f01[1];
    acc[2] += f23[0]; acc[3] += f23[1];
    acc[4] += f45[0]; acc[5] += f45[1];
    acc[6] += f67[0]; acc[7] += f67[1];
}

// ---------------- K5: layer-1 aggregate (fp8 gather, sigmoid) + fused layer-2 GEMM ----------------
// Phase 1: 16 thr/node x 16 nodes -> act row in LDS. Phase 2: 4 waves, each one
// 16x16 MFMA tile (K=128) of act @ W1 -> hs2 (fp16), scaled by dinv.
__global__ __launch_bounds__(256) void agg8_gemm2_kernel(
    const int* __restrict__ rowptr, const int* __restrict__ csr_src,
    const unsigned char* __restrict__ hs8, const float* __restrict__ dinv,
    const float* __restrict__ bias, const __half* __restrict__ wt1,
    __half* __restrict__ hs2, int n) {
    __shared__ _Float16 act_lds[16][136];   // 272B row: 16B-aligned, 2-way-bank free
    __shared__ float dinv_lds[16];
    const int tid  = threadIdx.x;
    const int nl   = tid >> 4;
    const int p    = tid & 15;
    const int node = blockIdx.x * 16 + nl;
    const bool valid = node < n;

    float acc[8];
    #pragma unroll
    for (int j = 0; j < 8; ++j) acc[j] = 0.0f;

    if (valid) {
        const unsigned char* __restrict__ hp = hs8 + p * 8;
        fp8x8_add(*(const uint2*)&hp[(size_t)node * 128], acc);   // self-loop

        int e        = rowptr[node];
        const int e1 = rowptr[node + 1];
        for (; e + 8 <= e1; e += 8) {
            int s[8];
            #pragma unroll
            for (int u = 0; u < 8; ++u) s[u] = csr_src[e + u];
            uint2 r[8];
            #pragma unroll
            for (int u = 0; u < 8; ++u) r[u] = *(const uint2*)&hp[(size_t)s[u] * 128];
            #pragma unroll
            for (int u = 0; u < 8; ++u) fp8x8_add(r[u], acc);
        }
        for (; e + 4 <= e1; e += 4) {
            int s[4];
            #pragma unroll
            for (int u = 0; u < 4; ++u) s[u] = csr_src[e + u];
            uint2 r[4];
            #pragma unroll
            for (int u = 0; u < 4; ++u) r[u] = *(const uint2*)&hp[(size_t)s[u] * 128];
            #pragma unroll
            for (int u = 0; u < 4; ++u) fp8x8_add(r[u], acc);
        }
        for (; e < e1; ++e) {
            int s = csr_src[e];
            fp8x8_add(*(const uint2*)&hp[(size_t)s * 128], acc);
        }

        const float sc = dinv[node];
        #pragma unroll
        for (int j = 0; j < 8; ++j) {
            float v = acc[j] * sc + bias[p * 8 + j];
            acc[j] = 1.0f / (1.0f + expf(-v));   // sigmoid
        }
    }
    #pragma unroll
    for (int j = 0; j < 8; ++j) act_lds[nl][p * 8 + j] = (_Float16)acc[j];
    if (p == 0) dinv_lds[nl] = valid ? dinv[node] : 0.0f;
    __syncthreads();

    // ---- phase 2: hs2[rows 16] = fp16((act @ W1) * dinv) ----
    const int wave  = tid >> 6;            // = output col tile ct
    const int lane  = tid & 63;
    const int l15   = lane & 15;
    const int khalf = lane >> 4;

    half8 a[4];
    #pragma unroll
    for (int ks = 0; ks < 4; ++ks)
        a[ks] = *(const half8*)&act_lds[l15][ks * 32 + khalf * 8];

    f32x4 acc2 = {0.f, 0.f, 0.f, 0.f};
    #pragma unroll
    for (int ks = 0; ks < 4; ++ks) {
        half8 bb = *(const half8*)&wt1[(size_t)(wave * 16 + l15) * 128 + ks * 32 + khalf * 8];
        acc2 = __builtin_amdgcn_mfma_f32_16x16x32_f16(a[ks], bb, acc2, 0, 0, 0);
    }
    const int col = wave * 16 + l15;
    _Float16* __restrict__ hs2f = (_Float16*)hs2;
    #pragma unroll
    for (int i = 0; i < 4; ++i) {
        int lr = khalf * 4 + i;
        int r  = blockIdx.x * 16 + lr;
        if (r < n) hs2f[(size_t)r * 64 + col] = (_Float16)(acc2[i] * dinv_lds[lr]);
    }
}

// ---------------- K6: layer-2 aggregate (fp16 hs2, fp32 out) ----------------
__global__ void aggregate64_kernel(const int* __restrict__ rowptr, const int* __restrict__ csr_src,
                                   const __half* __restrict__ hs, const float* __restrict__ dinv,
                                   const float* __restrict__ bias, float* __restrict__ out, int n) {
    const int tid  = threadIdx.x;
    const int node = blockIdx.x * 32 + (tid >> 3);
    const int p    = tid & 7;
    if (node >= n) return;

    const __half* __restrict__ hp = hs + (size_t)p * 8;

    float acc[8];
    {
        float4 raw = *(const float4*)&hp[(size_t)node * 64];
        const __half2* h2 = (const __half2*)&raw;
        #pragma unroll
        for (int j = 0; j < 4; ++j) {
            float2 f = __half22float2(h2[j]);
            acc[2 * j] = f.x; acc[2 * j + 1] = f.y;
        }
    }

    int e        = rowptr[node];
    const int e1 = rowptr[node + 1];

    for (; e + 8 <= e1; e += 8) {
        int s[8];
        #pragma unroll
        for (int u = 0; u < 8; ++u) s[u] = csr_src[e + u];
        float4 r[8];
        #pragma unroll
        for (int u = 0; u < 8; ++u) r[u] = *(const float4*)&hp[(size_t)s[u] * 64];
        #pragma unroll
        for (int j = 0; j < 4; ++j) {
            #pragma unroll
            for (int u = 0; u < 8; ++u) {
                float2 f = __half22float2(((const __half2*)&r[u])[j]);
                acc[2 * j] += f.x; acc[2 * j + 1] += f.y;
            }
        }
    }
    for (; e + 4 <= e1; e += 4) {
        int s[4];
        #pragma unroll
        for (int u = 0; u < 4; ++u) s[u] = csr_src[e + u];
        float4 r[4];
        #pragma unroll
        for (int u = 0; u < 4; ++u) r[u] = *(const float4*)&hp[(size_t)s[u] * 64];
        #pragma unroll
        for (int j = 0; j < 4; ++j) {
            #pragma unroll
            for (int u = 0; u < 4; ++u) {
                float2 f = __half22float2(((const __half2*)&r[u])[j]);
                acc[2 * j] += f.x; acc[2 * j + 1] += f.y;
            }
        }
    }
    for (; e < e1; ++e) {
        int s = csr_src[e];
        float4 r = *(const float4*)&hp[(size_t)s * 64];
        const __half2* a = (const __half2*)&r;
        #pragma unroll
        for (int j = 0; j < 4; ++j) {
            float2 f = __half22float2(a[j]);
            acc[2 * j] += f.x; acc[2 * j + 1] += f.y;
        }
    }

    const float sc = dinv[node];
    float* o = &out[(size_t)node * 64 + p * 8];
    #pragma unroll
    for (int j = 0; j < 8; ++j) acc[j] = acc[j] * sc + bias[p * 8 + j];
    *(float4*)&o[0] = make_float4(acc[0], acc[1], acc[2], acc[3]);
    *(float4*)&o[4] = make_float4(acc[4], acc[5], acc[6], acc[7]);
}

static inline size_t align256(size_t x) { return (x + 255) & ~size_t(255); }

extern "C" void kernel_launch(void* const* d_in, const int* in_sizes, int n_in,
                              void* d_out, int out_size, void* d_ws, size_t ws_size,
                              hipStream_t stream) {
    const float* x   = (const float*)d_in[0];
    const int*   e32 = (const int*)d_in[1];   // [2,E] int32
    const float* W0  = (const float*)d_in[2];
    const float* b0  = (const float*)d_in[3];
    const float* W1  = (const float*)d_in[4];
    const float* b1  = (const float*)d_in[5];
    float* out = (float*)d_out;

    const int N = in_sizes[0] / 128;   // 50000
    const int E = in_sizes[1] / 2;     // 800000
    const int* src = e32;
    const int* dst = e32 + E;

    const int nbkt = (N + 255) >> 8;          // 196 (requires N <= 65536 and src < 2^24)
    const int CB   = (E + 1023) >> 10;        // 782 chunk-blocks (<= 1024)
    const int WG   = (128 * 128 + 64 * 128 + BLK - 1) / BLK;  // 96 weight-convert blocks

    // Workspace layout
    char* p = (char*)d_ws;
    int*           countmat = (int*)p;           p += align256((size_t)CB * nbkt * 4);
    int*           total    = (int*)p;           p += align256((size_t)256 * 4);
    int*           bbase    = (int*)p;           p += align256((size_t)(nbkt + 1) * 4);
    unsigned*      sorted   = (unsigned*)p;      p += align256((size_t)E * 4);
    int*           rowptr   = (int*)p;           p += align256((size_t)(N + 1) * 4);
    float*         dinv     = (float*)p;         p += align256((size_t)N * 4);
    int*           csr_src  = (int*)p;           p += align256((size_t)E * 4);
    unsigned char* hs8      = (unsigned char*)p; p += align256((size_t)N * 128);      // fp8 layer-1 hs
    __half*        hs2      = (__half*)p;        p += align256((size_t)N * 64 * 2);   // fp16 layer-2 hs
    __half*        wt0      = (__half*)p;        p += align256((size_t)128 * 128 * 2);
    __half*        wt1      = (__half*)p;        p += align256((size_t)64 * 128 * 2);

    // ---- K1: chunk histograms + weight convert ----
    count_init_kernel<<<CB + WG, BLK, 0, stream>>>(dst, countmat, E, nbkt, CB, W0, W1, wt0, wt1);
    // ---- K2: per-bucket scan ----
    colscan_kernel<<<nbkt, BLK, 0, stream>>>(countmat, total, CB, nbkt);
    // ---- K3: packed scatter ----
    scatter_kernel<<<CB, BLK, 0, stream>>>(dst, src, countmat, total, sorted, bbase, E, nbkt);
    // ---- K4: CSR finalize + layer-1 GEMM ----
    csr_gemm1_kernel<<<nbkt, BLK, 0, stream>>>(sorted, bbase, rowptr, dinv, csr_src, N, E,
                                               x, wt0, hs8);
    // ---- K5: layer-1 aggregate + layer-2 GEMM ----
    agg8_gemm2_kernel<<<(N + 15) / 16, BLK, 0, stream>>>(rowptr, csr_src, hs8, dinv, b0, wt1,
                                                         hs2, N);
    // ---- K6: layer-2 aggregate ----
    aggregate64_kernel<<<(N + 31) / 32, BLK, 0, stream>>>(rowptr, csr_src, hs2, dinv, b1, out, N);
}